// Round 7
// baseline (291.228 us; speedup 1.0000x reference)
//
#include <hip/hip_runtime.h>
#include <math.h>

#define B_ 2
#define T_ 2048
#define C_ 1024
#define H_ 16
#define HD_ 64
#define M_ (B_*T_)

typedef _Float16 half2v __attribute__((ext_vector_type(2)));
typedef _Float16 half4v __attribute__((ext_vector_type(4)));
typedef _Float16 half8v __attribute__((ext_vector_type(8)));
typedef float f32x4 __attribute__((ext_vector_type(4)));

#define GLD_LDS(gp, lp) \
  __builtin_amdgcn_global_load_lds( \
      (const __attribute__((address_space(1))) void*)(gp), \
      (__attribute__((address_space(3))) void*)(lp), 16, 0, 0)

// ---------------------------------------------------------------------------
// Fused prep: fp32->f16 cast of x (blocks 0..4095), 4 weight transposes
// (blocks 4096..8191), bias concat (blocks 8192..8203). One launch.
// ---------------------------------------------------------------------------
__global__ __launch_bounds__(256) void prep_kernel(
    const float* __restrict__ x,
    const float* __restrict__ Wq, const float* __restrict__ Wk,
    const float* __restrict__ Wv, const float* __restrict__ Wo,
    const float* __restrict__ bq, const float* __restrict__ bk,
    const float* __restrict__ bv,
    _Float16* __restrict__ xh, _Float16* __restrict__ Wt3,
    _Float16* __restrict__ Wot, float* __restrict__ b3)
{
  __shared__ float tile[32][33];
  const int blk = blockIdx.x, thr = threadIdx.x;
  if (blk < 4096) {
    int i = blk * 256 + thr;
    float4 v = ((const float4*)x)[i];
    half4v h; h[0] = (_Float16)v.x; h[1] = (_Float16)v.y;
    h[2] = (_Float16)v.z; h[3] = (_Float16)v.w;
    ((half4v*)xh)[i] = h;
  } else if (blk < 8192) {
    int zz = (blk - 4096) >> 10;      // which W
    int bxy = (blk - 4096) & 1023;
    const float* W; _Float16* Wt;
    switch (zz) {
      case 0:  W = Wq; Wt = Wt3; break;
      case 1:  W = Wk; Wt = Wt3 + (size_t)1024 * 1024; break;
      case 2:  W = Wv; Wt = Wt3 + (size_t)2048 * 1024; break;
      default: W = Wo; Wt = Wot; break;
    }
    const int n0 = (bxy & 31) * 32, k0 = (bxy >> 5) * 32;
    const int tx = thr & 31, ty = thr >> 5;  // 32 x 8
#pragma unroll
    for (int r = 0; r < 4; r++) {
      int k = ty + r * 8;
      tile[k][tx] = W[(size_t)(k0 + k) * C_ + n0 + tx];
    }
    __syncthreads();
#pragma unroll
    for (int r = 0; r < 4; r++) {
      int n = ty + r * 8;
      Wt[(size_t)(n0 + n) * C_ + k0 + tx] = (_Float16)tile[tx][n];
    }
  } else {
    int i = (blk - 8192) * 256 + thr;  // 0..3071
    const float* s = (i < 1024) ? bq : ((i < 2048) ? bk : bv);
    b3[i] = s[i & 1023];
  }
}

// ---------------------------------------------------------------------------
// f16 MFMA GEMM: Out[M,N] = A[M,1024] @ Wt[N,1024]^T + bias.
// BK=32, 256 threads = 4 waves (2x2); wave tile (BM/2)x(BN/2).
// Staging via global_load_lds width=16 (m97 pattern).
// EPI 0: fused QKV epilogue. Q (scaled 0.125*log2e) and K: plain 2-B stores.
// V: packed 8-B stores to V^T.  EPI 1: fp32 out + bias (of).
// ---------------------------------------------------------------------------
template <int BM, int BN, int EPI>
__global__ __launch_bounds__(256) void gemm_f16_kernel(
    const _Float16* __restrict__ A, const _Float16* __restrict__ Bw,
    const float* __restrict__ bias,
    _Float16* __restrict__ o0, _Float16* __restrict__ o1,
    _Float16* __restrict__ o2, float* __restrict__ of)
{
  constexpr int FM = BM / 32, FN = BN / 32;
  __shared__ __align__(16) _Float16 As[BM * 32];
  __shared__ __align__(16) _Float16 Bs[BN * 32];
  const int t = threadIdx.x;
  const int w = t >> 6, lane = t & 63, l15 = lane & 15, quad = lane >> 4;
  const int wm = (w & 1) * (BM / 2), wn = (w >> 1) * (BN / 2);
  const int bm = blockIdx.y * BM, bn = blockIdx.x * BN;
  const int lrow = lane >> 2, lcol = (lane & 3) * 8;  // staging: 16 rows/call

  f32x4 acc[FM][FN];
#pragma unroll
  for (int i = 0; i < FM; i++)
#pragma unroll
    for (int j = 0; j < FN; j++) acc[i][j] = (f32x4){0.f, 0.f, 0.f, 0.f};

  for (int k0 = 0; k0 < 1024; k0 += 32) {
#pragma unroll
    for (int i = 0; i < BM / 64; i++) {
      int ca = w + 4 * i;
      int row = ca * 16 + lrow;
      GLD_LDS(A + (size_t)(bm + row) * 1024 + k0 + lcol, As + ca * 512);
    }
#pragma unroll
    for (int i = 0; i < BN / 64; i++) {
      int cb = w + 4 * i;
      int row = cb * 16 + lrow;
      GLD_LDS(Bw + (size_t)(bn + row) * 1024 + k0 + lcol, Bs + cb * 512);
    }
    __syncthreads();

    half8v af[FM], bf[FN];
#pragma unroll
    for (int mt = 0; mt < FM; mt++)
      af[mt] = *(const half8v*)(As + (wm + mt * 16 + l15) * 32 + quad * 8);
#pragma unroll
    for (int nt = 0; nt < FN; nt++)
      bf[nt] = *(const half8v*)(Bs + (wn + nt * 16 + l15) * 32 + quad * 8);
#pragma unroll
    for (int mt = 0; mt < FM; mt++)
#pragma unroll
      for (int nt = 0; nt < FN; nt++)
        acc[mt][nt] = __builtin_amdgcn_mfma_f32_16x16x32_f16(
            af[mt], bf[nt], acc[mt][nt], 0, 0, 0);
    __syncthreads();
  }

  // Epilogue. C/D layout: col = l15 (n), row = quad*4 + r (m).
#pragma unroll
  for (int mt = 0; mt < FM; mt++)
#pragma unroll
    for (int nt = 0; nt < FN; nt++) {
      int n = bn + wn + nt * 16 + l15;
      float bv = bias[n];
      if (EPI == 0 && bn >= 2048) {
        // V region: pack r=0..3 (consecutive t) -> one 8-B store to V^T.
        int dg = n - 2048;
        int hh = dg >> 6, hd = dg & 63;
        int m0 = bm + wm + mt * 16 + quad * 4;
        int bb = m0 >> 11, tt = m0 & 2047;
        half2v p01 = __builtin_bit_cast(half2v,
            __builtin_amdgcn_cvt_pkrtz(acc[mt][nt][0] + bv, acc[mt][nt][1] + bv));
        half2v p23 = __builtin_bit_cast(half2v,
            __builtin_amdgcn_cvt_pkrtz(acc[mt][nt][2] + bv, acc[mt][nt][3] + bv));
        half4v pk = __builtin_shufflevector(p01, p23, 0, 1, 2, 3);
        *(half4v*)(o2 + (((size_t)(bb * H_ + hh) * 64 + hd) * 2048 + tt)) = pk;
      } else {
#pragma unroll
        for (int r = 0; r < 4; r++) {
          int m = bm + wm + mt * 16 + quad * 4 + r;
          float v = acc[mt][nt][r] + bv;
          if (EPI == 0) {
            if (bn < 1024) {
              // Q pre-scaled by 0.125 * log2(e) for base-2 softmax.
              o0[(size_t)m * 1024 + n] = (_Float16)(v * 0.180336884f);
            } else {
              o1[(size_t)m * 1024 + (n - 1024)] = (_Float16)v;    // K
            }
          } else {
            of[(size_t)m * 1024 + n] = v;
          }
        }
      }
    }
}

// ---------------------------------------------------------------------------
// MFMA flash attention (no mask, per reference). Grid (T/128, H, B), 512 thr.
// V16 = V15's compute (unpermuted S^T, PV x32 dual-half4v, XCD swizzle,
// setprio) in round-3's KVBLK=64 double-buffered geometry (34.8 KB LDS,
// 2 blocks/CU proven), with the T14 issue-early/write-late split:
//   per tile: [barrier] issue next tile's 2 global loads -> regs;
//             sched_barrier(0) PINS the issue before compute (round 3's
//             regression: hipcc sank the unpinned loads to the ds_write,
//             exposing full latency -- plus no XCD swizzle meant ~900 cy
//             HBM latency/tile, matching its 2.5x loss exactly);
//             compute tile from buf[it&1];
//             ds_write regs -> buf[(it+1)&1] (vmcnt wait lands here,
//             after ~350 cy of compute covers the ~200 cy L2 latency);
//             barrier.
// Safety: buf[(it+1)&1]'s last reader is compute(it-1); barrier(it-1)
// orders all waves' compute(it-1) before any wave's write in iter it.
// Wave w (0..7) owns q-cols qt*128 + w*16 + l15. Base-2 softmax.
// ---------------------------------------------------------------------------
__global__ __launch_bounds__(512) void attn_f16_kernel(
    const _Float16* __restrict__ Qh, const _Float16* __restrict__ Kh,
    const _Float16* __restrict__ Vt, _Float16* __restrict__ Yh)
{
  __shared__ __align__(16) _Float16 Ks[2][64 * 68];   // [key][d], 136-B rows
  __shared__ __align__(16) _Float16 Vs[2][64 * 68];   // [d][t],   136-B rows
  const int t = threadIdx.x;
  const int w = t >> 6, lane = t & 63, l15 = lane & 15, quad = lane >> 4;
  // XCD-aware bijective remap (round-5-proven: FETCH 69.7 -> 12.3 MB).
  const int lin = blockIdx.x + 16 * blockIdx.y + 256 * blockIdx.z;
  const int swz = (lin & 7) * 64 + (lin >> 3);
  const int qt = swz & 15, h = (swz >> 4) & 15, b = swz >> 8;
  const int qg = qt * 128 + w * 16 + l15;
  const size_t qoff = ((size_t)(b * T_ + qg)) * C_ + h * HD_;

  half8v qf[2];
  qf[0] = *(const half8v*)(Qh + qoff + quad * 8);
  qf[1] = *(const half8v*)(Qh + qoff + 32 + quad * 8);

  f32x4 o[4];
#pragma unroll
  for (int i = 0; i < 4; i++) o[i] = (f32x4){0.f, 0.f, 0.f, 0.f};
  float m_run = -INFINITY, l_run = 0.f;

  const size_t kbase = ((size_t)b * T_) * C_ + h * HD_;
  const size_t vbase = ((size_t)(b * H_ + h)) * HD_ * 2048;

  // Staging: 512 16-B chunks per matrix per tile, 1 per thread.
  // K: row = key (64 rows x 128 B); V: row = d (64 rows x 128 B).
  const int srow = t >> 3, scp = t & 7;
  const int lds_off = srow * 136 + scp * 16;      // byte offset within a tile
  const _Float16* kp = Kh + kbase + (size_t)srow * C_ + scp * 8;
  const _Float16* vp = Vt + vbase + (size_t)srow * 2048 + scp * 8;

  // Prologue: tile 0 regs -> LDS buf 0.
  uint4 kr = *(const uint4*)kp;
  uint4 vr = *(const uint4*)vp;
  *(uint4*)((char*)Ks[0] + lds_off) = kr;
  *(uint4*)((char*)Vs[0] + lds_off) = vr;
  __syncthreads();

  for (int it = 0; it < 32; ++it) {
    const char* Ksb = (const char*)Ks[it & 1];
    const char* Vsb = (const char*)Vs[it & 1];

    // Issue next tile's loads NOW; sched_barrier pins them before compute.
    if (it + 1 < 32) {
      kp += (size_t)64 * C_;
      vp += 64;
      kr = *(const uint4*)kp;
      vr = *(const uint4*)vp;
      __builtin_amdgcn_sched_barrier(0);
    }

    // S^T tiles: 4 key-tiles x 2 d-steps of 16x16x32.
    f32x4 s[4];
    __builtin_amdgcn_s_setprio(1);
#pragma unroll
    for (int kt = 0; kt < 4; kt++) {
      s[kt] = (f32x4){0.f, 0.f, 0.f, 0.f};
      int key = kt * 16 + l15;
#pragma unroll
      for (int ks = 0; ks < 2; ks++) {
        half8v kf = *(const half8v*)(Ksb + key * 136 + (ks * 4 + quad) * 16);
        s[kt] = __builtin_amdgcn_mfma_f32_16x16x32_f16(kf, qf[ks], s[kt], 0, 0, 0);
      }
    }
    __builtin_amdgcn_s_setprio(0);

    // Online softmax (base-2) over the 64 keys, per q column = l15.
    float tmax = -INFINITY;
#pragma unroll
    for (int kt = 0; kt < 4; kt++)
#pragma unroll
      for (int r = 0; r < 4; r++) tmax = fmaxf(tmax, s[kt][r]);
    tmax = fmaxf(tmax, __shfl_xor(tmax, 16));
    tmax = fmaxf(tmax, __shfl_xor(tmax, 32));
    float mnew = fmaxf(m_run, tmax);
    float alpha = __builtin_amdgcn_exp2f(m_run - mnew);

    float psum = 0.f;
    half4v pf[4];
#pragma unroll
    for (int kt = 0; kt < 4; kt++) {
      float p0 = __builtin_amdgcn_exp2f(s[kt][0] - mnew);
      float p1 = __builtin_amdgcn_exp2f(s[kt][1] - mnew);
      float p2 = __builtin_amdgcn_exp2f(s[kt][2] - mnew);
      float p3 = __builtin_amdgcn_exp2f(s[kt][3] - mnew);
      psum += (p0 + p1) + (p2 + p3);
      half2v pk01 = __builtin_bit_cast(half2v, __builtin_amdgcn_cvt_pkrtz(p0, p1));
      half2v pk23 = __builtin_bit_cast(half2v, __builtin_amdgcn_cvt_pkrtz(p2, p3));
      pf[kt] = __builtin_shufflevector(pk01, pk23, 0, 1, 2, 3);
    }
    psum += __shfl_xor(psum, 16);
    psum += __shfl_xor(psum, 32);
    l_run = l_run * alpha + psum;
    m_run = mnew;
#pragma unroll
    for (int dt = 0; dt < 4; dt++) o[dt] *= alpha;

    // PV: o^T[d][q] += V^T x P, 4 d-tiles x 2 key-groups of 16x16x32.
    // pf[2p] holds P[32p+4q+(0..3)][q], pf[2p+1] holds P[32p+16+4q+(0..3)][q];
    // concat is a valid x32 B-operand when the V^T A-operand supplies the
    // SAME keys in the same (q,j) slots: two half4v at d*136 + p*64 + q*8
    // and +32 (consistent k-permutation on both operands).
    __builtin_amdgcn_s_setprio(1);
#pragma unroll
    for (int dt = 0; dt < 4; dt++) {
      int d = dt * 16 + l15;
#pragma unroll
      for (int p = 0; p < 2; p++) {
        half4v v0 = *(const half4v*)(Vsb + d * 136 + p * 64 + quad * 8);
        half4v v1 = *(const half4v*)(Vsb + d * 136 + p * 64 + 32 + quad * 8);
        half8v vf = __builtin_shufflevector(v0, v1, 0, 1, 2, 3, 4, 5, 6, 7);
        half8v pf8 = __builtin_shufflevector(pf[2 * p], pf[2 * p + 1],
                                             0, 1, 2, 3, 4, 5, 6, 7);
        o[dt] = __builtin_amdgcn_mfma_f32_16x16x32_f16(vf, pf8, o[dt], 0, 0, 0);
      }
    }
    __builtin_amdgcn_s_setprio(0);

    // Write next tile (vmcnt wait for kr/vr lands here, after compute).
    if (it + 1 < 32) {
      *(uint4*)((char*)Ks[(it + 1) & 1] + lds_off) = kr;
      *(uint4*)((char*)Vs[(it + 1) & 1] + lds_off) = vr;
    }
    __syncthreads();
  }

  float inv = 1.0f / l_run;
#pragma unroll
  for (int dt = 0; dt < 4; dt++) {
    half4v yv;
#pragma unroll
    for (int r = 0; r < 4; r++) yv[r] = (_Float16)(o[dt][r] * inv);
    *(half4v*)(Yh + qoff + dt * 16 + quad * 4) = yv;  // row q, cols h*64+d..
  }
}

// ---------------------------------------------------------------------------
extern "C" void kernel_launch(void* const* d_in, const int* in_sizes, int n_in,
                              void* d_out, int out_size, void* d_ws, size_t ws_size,
                              hipStream_t stream) {
  const float* x  = (const float*)d_in[0];
  const float* Wq = (const float*)d_in[1];
  const float* bq = (const float*)d_in[2];
  const float* Wk = (const float*)d_in[3];
  const float* bk = (const float*)d_in[4];
  const float* Wv = (const float*)d_in[5];
  const float* bv = (const float*)d_in[6];
  const float* Wo = (const float*)d_in[7];
  const float* bo = (const float*)d_in[8];
  float* out = (float*)d_out;

  // Workspace carve-up (bytes). Each f16 plane M_*C_ = 8 MB.
  char* ws = (char*)d_ws;
  _Float16* xh   = (_Float16*)(ws);                        // 8 MB
  _Float16* Qh   = (_Float16*)(ws + (((size_t)8)  << 20)); // 8 MB
  _Float16* Kh   = (_Float16*)(ws + (((size_t)16) << 20)); // 8 MB
  _Float16* Vt   = (_Float16*)(ws + (((size_t)24) << 20)); // 8 MB  [b,h,d,t]
  _Float16* Yh   = (_Float16*)(ws + (((size_t)32) << 20)); // 8 MB
  _Float16* Wt3  = (_Float16*)(ws + (((size_t)40) << 20)); // 6 MB  [3072][1024]
  _Float16* Wot  = (_Float16*)(ws + (((size_t)46) << 20)); // 2 MB  [1024][1024]
  float*    b3   = (float*)   (ws + (((size_t)48) << 20)); // 12 KB

  prep_kernel<<<8204, 256, 0, stream>>>(x, Wq, Wk, Wv, Wo, bq, bk, bv,
                                        xh, Wt3, Wot, b3);

  // Fused QKV projection: [4096,1024] @ [1024,3072] -> Q,K (f16) + V^T (f16).
  gemm_f16_kernel<128, 128, 0><<<dim3(24, 32), 256, 0, stream>>>(
      xh, Wt3, b3, Qh, Kh, Vt, nullptr);

  attn_f16_kernel<<<dim3(T_ / 128, H_, B_), 512, 0, stream>>>(Qh, Kh, Vt, Yh);

  // Output projection: Yh @ Wot^T + bo -> fp32 out.
  gemm_f16_kernel<64, 128, 1><<<dim3(8, 64), 256, 0, stream>>>(
      Yh, Wot, bo, nullptr, nullptr, nullptr, out);
}

// Round 8
// 204.369 us; speedup vs baseline: 1.4250x; 1.4250x over previous
//
#include <hip/hip_runtime.h>
#include <math.h>

#define B_ 2
#define T_ 2048
#define C_ 1024
#define H_ 16
#define HD_ 64
#define M_ (B_*T_)

typedef _Float16 half2v __attribute__((ext_vector_type(2)));
typedef _Float16 half4v __attribute__((ext_vector_type(4)));
typedef _Float16 half8v __attribute__((ext_vector_type(8)));
typedef float f32x4 __attribute__((ext_vector_type(4)));

#define GLD_LDS(gp, lp) \
  __builtin_amdgcn_global_load_lds( \
      (const __attribute__((address_space(1))) void*)(gp), \
      (__attribute__((address_space(3))) void*)(lp), 16, 0, 0)

// ---------------------------------------------------------------------------
// Fused prep: fp32->f16 cast of x (blocks 0..4095), 4 weight transposes
// (blocks 4096..8191), bias concat (blocks 8192..8203). One launch.
// ---------------------------------------------------------------------------
__global__ __launch_bounds__(256) void prep_kernel(
    const float* __restrict__ x,
    const float* __restrict__ Wq, const float* __restrict__ Wk,
    const float* __restrict__ Wv, const float* __restrict__ Wo,
    const float* __restrict__ bq, const float* __restrict__ bk,
    const float* __restrict__ bv,
    _Float16* __restrict__ xh, _Float16* __restrict__ Wt3,
    _Float16* __restrict__ Wot, float* __restrict__ b3)
{
  __shared__ float tile[32][33];
  const int blk = blockIdx.x, thr = threadIdx.x;
  if (blk < 4096) {
    int i = blk * 256 + thr;
    float4 v = ((const float4*)x)[i];
    half4v h; h[0] = (_Float16)v.x; h[1] = (_Float16)v.y;
    h[2] = (_Float16)v.z; h[3] = (_Float16)v.w;
    ((half4v*)xh)[i] = h;
  } else if (blk < 8192) {
    int zz = (blk - 4096) >> 10;      // which W
    int bxy = (blk - 4096) & 1023;
    const float* W; _Float16* Wt;
    switch (zz) {
      case 0:  W = Wq; Wt = Wt3; break;
      case 1:  W = Wk; Wt = Wt3 + (size_t)1024 * 1024; break;
      case 2:  W = Wv; Wt = Wt3 + (size_t)2048 * 1024; break;
      default: W = Wo; Wt = Wot; break;
    }
    const int n0 = (bxy & 31) * 32, k0 = (bxy >> 5) * 32;
    const int tx = thr & 31, ty = thr >> 5;  // 32 x 8
#pragma unroll
    for (int r = 0; r < 4; r++) {
      int k = ty + r * 8;
      tile[k][tx] = W[(size_t)(k0 + k) * C_ + n0 + tx];
    }
    __syncthreads();
#pragma unroll
    for (int r = 0; r < 4; r++) {
      int n = ty + r * 8;
      Wt[(size_t)(n0 + n) * C_ + k0 + tx] = (_Float16)tile[tx][n];
    }
  } else {
    int i = (blk - 8192) * 256 + thr;  // 0..3071
    const float* s = (i < 1024) ? bq : ((i < 2048) ? bk : bv);
    b3[i] = s[i & 1023];
  }
}

// ---------------------------------------------------------------------------
// f16 MFMA GEMM: Out[M,N] = A[M,1024] @ Wt[N,1024]^T + bias.
// BK=32, 256 threads = 4 waves (2x2); wave tile (BM/2)x(BN/2).
// Staging via global_load_lds width=16 (m97 pattern).
// EPI 0: fused QKV epilogue. Q (scaled 0.125*log2e) and K: plain 2-B stores.
// V: packed 8-B stores to V^T.  EPI 1: fp32 out + bias (of).
// ---------------------------------------------------------------------------
template <int BM, int BN, int EPI>
__global__ __launch_bounds__(256) void gemm_f16_kernel(
    const _Float16* __restrict__ A, const _Float16* __restrict__ Bw,
    const float* __restrict__ bias,
    _Float16* __restrict__ o0, _Float16* __restrict__ o1,
    _Float16* __restrict__ o2, float* __restrict__ of)
{
  constexpr int FM = BM / 32, FN = BN / 32;
  __shared__ __align__(16) _Float16 As[BM * 32];
  __shared__ __align__(16) _Float16 Bs[BN * 32];
  const int t = threadIdx.x;
  const int w = t >> 6, lane = t & 63, l15 = lane & 15, quad = lane >> 4;
  const int wm = (w & 1) * (BM / 2), wn = (w >> 1) * (BN / 2);
  const int bm = blockIdx.y * BM, bn = blockIdx.x * BN;
  const int lrow = lane >> 2, lcol = (lane & 3) * 8;  // staging: 16 rows/call

  f32x4 acc[FM][FN];
#pragma unroll
  for (int i = 0; i < FM; i++)
#pragma unroll
    for (int j = 0; j < FN; j++) acc[i][j] = (f32x4){0.f, 0.f, 0.f, 0.f};

  for (int k0 = 0; k0 < 1024; k0 += 32) {
#pragma unroll
    for (int i = 0; i < BM / 64; i++) {
      int ca = w + 4 * i;
      int row = ca * 16 + lrow;
      GLD_LDS(A + (size_t)(bm + row) * 1024 + k0 + lcol, As + ca * 512);
    }
#pragma unroll
    for (int i = 0; i < BN / 64; i++) {
      int cb = w + 4 * i;
      int row = cb * 16 + lrow;
      GLD_LDS(Bw + (size_t)(bn + row) * 1024 + k0 + lcol, Bs + cb * 512);
    }
    __syncthreads();

    half8v af[FM], bf[FN];
#pragma unroll
    for (int mt = 0; mt < FM; mt++)
      af[mt] = *(const half8v*)(As + (wm + mt * 16 + l15) * 32 + quad * 8);
#pragma unroll
    for (int nt = 0; nt < FN; nt++)
      bf[nt] = *(const half8v*)(Bs + (wn + nt * 16 + l15) * 32 + quad * 8);
#pragma unroll
    for (int mt = 0; mt < FM; mt++)
#pragma unroll
      for (int nt = 0; nt < FN; nt++)
        acc[mt][nt] = __builtin_amdgcn_mfma_f32_16x16x32_f16(
            af[mt], bf[nt], acc[mt][nt], 0, 0, 0);
    __syncthreads();
  }

  // Epilogue. C/D layout: col = l15 (n), row = quad*4 + r (m).
#pragma unroll
  for (int mt = 0; mt < FM; mt++)
#pragma unroll
    for (int nt = 0; nt < FN; nt++) {
      int n = bn + wn + nt * 16 + l15;
      float bv = bias[n];
      if (EPI == 0 && bn >= 2048) {
        // V region: pack r=0..3 (consecutive t) -> one 8-B store to V^T.
        int dg = n - 2048;
        int hh = dg >> 6, hd = dg & 63;
        int m0 = bm + wm + mt * 16 + quad * 4;
        int bb = m0 >> 11, tt = m0 & 2047;
        half2v p01 = __builtin_bit_cast(half2v,
            __builtin_amdgcn_cvt_pkrtz(acc[mt][nt][0] + bv, acc[mt][nt][1] + bv));
        half2v p23 = __builtin_bit_cast(half2v,
            __builtin_amdgcn_cvt_pkrtz(acc[mt][nt][2] + bv, acc[mt][nt][3] + bv));
        half4v pk = __builtin_shufflevector(p01, p23, 0, 1, 2, 3);
        *(half4v*)(o2 + (((size_t)(bb * H_ + hh) * 64 + hd) * 2048 + tt)) = pk;
      } else {
#pragma unroll
        for (int r = 0; r < 4; r++) {
          int m = bm + wm + mt * 16 + quad * 4 + r;
          float v = acc[mt][nt][r] + bv;
          if (EPI == 0) {
            if (bn < 1024) {
              // Q pre-scaled by 0.125 * log2(e) for base-2 softmax.
              o0[(size_t)m * 1024 + n] = (_Float16)(v * 0.180336884f);
            } else {
              o1[(size_t)m * 1024 + (n - 1024)] = (_Float16)v;    // K
            }
          } else {
            of[(size_t)m * 1024 + n] = v;
          }
        }
      }
    }
}

// ---------------------------------------------------------------------------
// MFMA flash attention (no mask, per reference). Grid (T/128, H, B), 512 thr.
// V17 = V15/round-6 frame EXACTLY (KVBLK=128, single LDS buffer, ds_write at
// TOP, two barriers/tile -- the proven 62.3 us structure) with ONE change:
// T14 issue-early. The 4 global loads for tile it+1 are issued mid-compute
// (after the S^T cluster), UNCONDITIONALLY in the main straight-line block,
// pinned by sched_barrier(0). Rounds 2/3/7 post-mortem: conditional loads in
// their own basic block got SUNK to the ds_write (r7 VGPR=36 < r6's 48 is
// the tell), serializing load latency; unconditional same-block loads can't
// be sunk. ds_write ordering is byte-identical to round 6 (after barrier2),
// so even if scheduling degrades, the floor is round-6 behavior (~62 us).
// Tail (it=15) prefetches a 17th tile: addresses stay inside the workspace
// (spill into the adjacent Vt/Yh planes), values never used.
// VGPR tell: ~64-70 = prefetch held; ~48 = sunk (neutral).
// Other carried wins: PV x32 dual-half4v (r6), bijective XCD swizzle
// (r5: FETCH 69.7->12.3 MB), s_setprio around MFMA (T5).
// ---------------------------------------------------------------------------
__global__ __launch_bounds__(512) void attn_f16_kernel(
    const _Float16* __restrict__ Qh, const _Float16* __restrict__ Kh,
    const _Float16* __restrict__ Vt, _Float16* __restrict__ Yh)
{
  __shared__ __align__(16) _Float16 Ks[128 * 68];   // [key][d], 136-B rows
  __shared__ __align__(16) _Float16 Vs[64 * 132];   // [d][t], 264-B rows
  const int t = threadIdx.x;
  const int w = t >> 6, lane = t & 63, l15 = lane & 15, quad = lane >> 4;
  // XCD-aware bijective remap (round-5-proven).
  const int lin = blockIdx.x + 16 * blockIdx.y + 256 * blockIdx.z;
  const int swz = (lin & 7) * 64 + (lin >> 3);
  const int qt = swz & 15, h = (swz >> 4) & 15, b = swz >> 8;
  const int qg = qt * 128 + w * 16 + l15;
  const size_t qoff = ((size_t)(b * T_ + qg)) * C_ + h * HD_;

  half8v qf[2];
  qf[0] = *(const half8v*)(Qh + qoff + quad * 8);
  qf[1] = *(const half8v*)(Qh + qoff + 32 + quad * 8);

  f32x4 o[4];
#pragma unroll
  for (int i = 0; i < 4; i++) o[i] = (f32x4){0.f, 0.f, 0.f, 0.f};
  float m_run = -INFINITY, l_run = 0.f;

  const size_t kbase = ((size_t)b * T_) * C_ + h * HD_;
  const size_t vbase = ((size_t)(b * H_ + h)) * HD_ * 2048;

  // Fixed per-thread staging coordinates (1024 16-B chunks, 2/thread each).
  const int ks0 = t, ks1 = t + 512;
  const int krow0 = ks0 >> 3, kcp0 = ks0 & 7;
  const int krow1 = ks1 >> 3, kcp1 = ks1 & 7;
  const int vrow0 = ks0 >> 4, vcp0 = ks0 & 15;
  const int vrow1 = ks1 >> 4, vcp1 = ks1 & 15;
  const _Float16* kp0 = Kh + kbase + (size_t)krow0 * C_ + kcp0 * 8;
  const _Float16* kp1 = Kh + kbase + (size_t)krow1 * C_ + kcp1 * 8;
  const _Float16* vp0 = Vt + vbase + (size_t)vrow0 * 2048 + vcp0 * 8;
  const _Float16* vp1 = Vt + vbase + (size_t)vrow1 * 2048 + vcp1 * 8;

  // Prologue: tile 0 -> regs.
  uint4 kr0 = *(const uint4*)kp0, kr1 = *(const uint4*)kp1;
  uint4 vr0 = *(const uint4*)vp0, vr1 = *(const uint4*)vp1;

  for (int it = 0; it < 16; ++it) {
    // Stage current tile: regs -> LDS (vmcnt wait inserted by compiler).
    *(uint4*)((char*)Ks + krow0 * 136 + kcp0 * 16) = kr0;
    *(uint4*)((char*)Ks + krow1 * 136 + kcp1 * 16) = kr1;
    *(uint4*)((char*)Vs + vrow0 * 264 + vcp0 * 16) = vr0;
    *(uint4*)((char*)Vs + vrow1 * 264 + vcp1 * 16) = vr1;
    __syncthreads();

    // S^T tiles: 8 key-tiles x 2 d-steps of 16x16x32.
    f32x4 s[8];
    __builtin_amdgcn_s_setprio(1);
#pragma unroll
    for (int kt = 0; kt < 8; kt++) {
      s[kt] = (f32x4){0.f, 0.f, 0.f, 0.f};
      int key = kt * 16 + l15;
#pragma unroll
      for (int ks = 0; ks < 2; ks++) {
        half8v kf = *(const half8v*)((char*)Ks + key * 136 + (ks * 4 + quad) * 16);
        s[kt] = __builtin_amdgcn_mfma_f32_16x16x32_f16(kf, qf[ks], s[kt], 0, 0, 0);
      }
    }
    __builtin_amdgcn_s_setprio(0);

    // T14 issue-early: prefetch tile it+1 NOW (unconditional, same block;
    // latency hides under softmax+PV). sched_barrier pins the issue point.
    kp0 += 128 * (size_t)C_;  kp1 += 128 * (size_t)C_;
    vp0 += 128;               vp1 += 128;
    kr0 = *(const uint4*)kp0; kr1 = *(const uint4*)kp1;
    vr0 = *(const uint4*)vp0; vr1 = *(const uint4*)vp1;
    __builtin_amdgcn_sched_barrier(0);

    // Online softmax (base-2) over the 128 keys, per q column = l15.
    float tmax = -INFINITY;
#pragma unroll
    for (int kt = 0; kt < 8; kt++)
#pragma unroll
      for (int r = 0; r < 4; r++) tmax = fmaxf(tmax, s[kt][r]);
    tmax = fmaxf(tmax, __shfl_xor(tmax, 16));
    tmax = fmaxf(tmax, __shfl_xor(tmax, 32));
    float mnew = fmaxf(m_run, tmax);
    float alpha = __builtin_amdgcn_exp2f(m_run - mnew);

    float psum = 0.f;
    half4v pf[8];
#pragma unroll
    for (int kt = 0; kt < 8; kt++) {
      float p0 = __builtin_amdgcn_exp2f(s[kt][0] - mnew);
      float p1 = __builtin_amdgcn_exp2f(s[kt][1] - mnew);
      float p2 = __builtin_amdgcn_exp2f(s[kt][2] - mnew);
      float p3 = __builtin_amdgcn_exp2f(s[kt][3] - mnew);
      psum += (p0 + p1) + (p2 + p3);
      half2v pk01 = __builtin_bit_cast(half2v, __builtin_amdgcn_cvt_pkrtz(p0, p1));
      half2v pk23 = __builtin_bit_cast(half2v, __builtin_amdgcn_cvt_pkrtz(p2, p3));
      pf[kt] = __builtin_shufflevector(pk01, pk23, 0, 1, 2, 3);
    }
    psum += __shfl_xor(psum, 16);
    psum += __shfl_xor(psum, 32);
    l_run = l_run * alpha + psum;
    m_run = mnew;
#pragma unroll
    for (int dt = 0; dt < 4; dt++) o[dt] *= alpha;

    // PV: o^T[d][q] += V^T x P, 4 d-tiles x 4 key-groups of 16x16x32.
    // pf[2p] holds P[32p+4q+(0..3)][q], pf[2p+1] holds P[32p+16+4q+(0..3)][q]
    // -> concat is the x32 B-operand (k=8q+j). Matching V^T A-operand:
    // two half4v at d*264 + p*64 + q*8 (+32) -- same addresses round 1 read.
    __builtin_amdgcn_s_setprio(1);
#pragma unroll
    for (int dt = 0; dt < 4; dt++) {
      int d = dt * 16 + l15;
#pragma unroll
      for (int p = 0; p < 4; p++) {
        half4v v0 = *(const half4v*)((char*)Vs + d * 264 + p * 64 + quad * 8);
        half4v v1 = *(const half4v*)((char*)Vs + d * 264 + p * 64 + 32 + quad * 8);
        half8v vf = __builtin_shufflevector(v0, v1, 0, 1, 2, 3, 4, 5, 6, 7);
        half8v pf8 = __builtin_shufflevector(pf[2 * p], pf[2 * p + 1],
                                             0, 1, 2, 3, 4, 5, 6, 7);
        o[dt] = __builtin_amdgcn_mfma_f32_16x16x32_f16(vf, pf8, o[dt], 0, 0, 0);
      }
    }
    __builtin_amdgcn_s_setprio(0);
    __syncthreads();
  }

  float inv = 1.0f / l_run;
#pragma unroll
  for (int dt = 0; dt < 4; dt++) {
    half4v yv;
#pragma unroll
    for (int r = 0; r < 4; r++) yv[r] = (_Float16)(o[dt][r] * inv);
    *(half4v*)(Yh + qoff + dt * 16 + quad * 4) = yv;  // row q, cols h*64+d..
  }
}

// ---------------------------------------------------------------------------
extern "C" void kernel_launch(void* const* d_in, const int* in_sizes, int n_in,
                              void* d_out, int out_size, void* d_ws, size_t ws_size,
                              hipStream_t stream) {
  const float* x  = (const float*)d_in[0];
  const float* Wq = (const float*)d_in[1];
  const float* bq = (const float*)d_in[2];
  const float* Wk = (const float*)d_in[3];
  const float* bk = (const float*)d_in[4];
  const float* Wv = (const float*)d_in[5];
  const float* bv = (const float*)d_in[6];
  const float* Wo = (const float*)d_in[7];
  const float* bo = (const float*)d_in[8];
  float* out = (float*)d_out;

  // Workspace carve-up (bytes). Each f16 plane M_*C_ = 8 MB.
  char* ws = (char*)d_ws;
  _Float16* xh   = (_Float16*)(ws);                        // 8 MB
  _Float16* Qh   = (_Float16*)(ws + (((size_t)8)  << 20)); // 8 MB
  _Float16* Kh   = (_Float16*)(ws + (((size_t)16) << 20)); // 8 MB
  _Float16* Vt   = (_Float16*)(ws + (((size_t)24) << 20)); // 8 MB  [b,h,d,t]
  _Float16* Yh   = (_Float16*)(ws + (((size_t)32) << 20)); // 8 MB
  _Float16* Wt3  = (_Float16*)(ws + (((size_t)40) << 20)); // 6 MB  [3072][1024]
  _Float16* Wot  = (_Float16*)(ws + (((size_t)46) << 20)); // 2 MB  [1024][1024]
  float*    b3   = (float*)   (ws + (((size_t)48) << 20)); // 12 KB

  prep_kernel<<<8204, 256, 0, stream>>>(x, Wq, Wk, Wv, Wo, bq, bk, bv,
                                        xh, Wt3, Wot, b3);

  // Fused QKV projection: [4096,1024] @ [1024,3072] -> Q,K (f16) + V^T (f16).
  gemm_f16_kernel<128, 128, 0><<<dim3(24, 32), 256, 0, stream>>>(
      xh, Wt3, b3, Qh, Kh, Vt, nullptr);

  attn_f16_kernel<<<dim3(T_ / 128, H_, B_), 512, 0, stream>>>(Qh, Kh, Vt, Yh);

  // Output projection: Yh @ Wot^T + bo -> fp32 out.
  gemm_f16_kernel<64, 128, 1><<<dim3(8, 64), 256, 0, stream>>>(
      Yh, Wot, bo, nullptr, nullptr, nullptr, out);
}